// Round 2
// baseline (2496.314 us; speedup 1.0000x reference)
//
#include <hip/hip_runtime.h>

// Sliding-window bandwidth-weighted regression moments.
// B=4, H=720, W=1280, C=3, win=11 (R=5), bandwidth=0.5 -> inv_bw2=4.
// Outputs (concatenated): x/wsum, xx/wsum, xy/wsum, y/wsum, each [B,H,W,C] fp32.
//
// R4 -> R5: occupancy-first restructure.
//  - Tile 64x16 -> 32x16 (KX=2). LDS 48KB -> 25.6KB => 6 blocks/CU
//    (24 waves/CU, 6 waves/SIMD) instead of 3 blocks/CU (3 waves/SIMD).
//  - Persistent regs 64 -> 32 (26 accumulators + 6 center colors).
//  - LSTR=42 (=LW, no pad). Row reads as ds_read_b64: quarter-wave = one ty
//    row covers all 32 banks exactly once -> conflict-free minimum phases.
//    One base address per dy; all 36 reads use offset immediates.
//  - exp2f -> __builtin_amdgcn_exp2f (raw v_exp_f32; sentinel still -> w=0).
//  - Epilogue restaged for 32-wide tile (float2 stage, float4 stores).

#define HH   720
#define WW   1280
#define BB   4
#define RAD  5
#define TX   32      // tile width  (16 threads x KX=2)
#define TY   16      // tile height (16 threads)
#define KX   2
#define LW   42      // tile cols incl. halo
#define LH   26      // tile rows incl. halo
#define LSTR 42      // == LW, rows 8B-aligned per thread (tx*2 even)
#define PLANE (LSTR * LH)          // 1092 floats
#define LDS_FLOATS (6 * PLANE)     // 6552 floats = 26208 B -> 6 blocks/CU

__global__ __launch_bounds__(256, 6)
void regression_kernel(const float* __restrict__ rnd,
                       const float* __restrict__ tgt,
                       float* __restrict__ out)
{
    __shared__ __align__(16) float lds[LDS_FLOATS];
    float* pt0 = lds;
    float* pt1 = lds + PLANE;
    float* pt2 = lds + 2 * PLANE;
    float* pr0 = lds + 3 * PLANE;
    float* pr1 = lds + 4 * PLANE;
    float* pr2 = lds + 5 * PLANE;

    const int tx = threadIdx.x;        // 0..15
    const int ty = threadIdx.y;        // 0..15
    const int tid = ty * 16 + tx;
    const int X0 = blockIdx.x * TX;
    const int Y0 = blockIdx.y * TY;
    const int b  = blockIdx.z;

    const float SENT = 1e19f;          // OOB sentinel: d ~ 1e38 -> w = 0 exactly

    // ---- stage tile (42x26, sentinel for OOB) into 6 SoA planes ----
    for (int i = tid; i < PLANE; i += 256) {
        int ly = i / LSTR;
        int lx = i - ly * LSTR;
        int gy = Y0 + ly - RAD;
        int gx = X0 + lx - RAD;
        float t0 = SENT, t1 = SENT, t2 = SENT, r0 = 0.f, r1 = 0.f, r2 = 0.f;
        if ((unsigned)gy < (unsigned)HH && (unsigned)gx < (unsigned)WW) {
            int off = ((b * HH + gy) * WW + gx) * 3;
            t0 = tgt[off + 0]; t1 = tgt[off + 1]; t2 = tgt[off + 2];
            r0 = rnd[off + 0]; r1 = rnd[off + 1]; r2 = rnd[off + 2];
        }
        pt0[i] = t0; pt1[i] = t1; pt2[i] = t2;
        pr0[i] = r0; pr1[i] = r1; pr2[i] = r2;
    }
    __syncthreads();

    // ---- center guide colors for the 2-px strip (always in-image) ----
    float tp0[KX], tp1[KX], tp2[KX];
    {
        int s = (ty + RAD) * LSTR + tx * KX + RAD;
        #pragma unroll
        for (int k = 0; k < KX; ++k) {
            tp0[k] = pt0[s + k]; tp1[k] = pt1[s + k]; tp2[k] = pt2[s + k];
        }
    }

    float sx0[KX] = {}, sx1[KX] = {}, sx2[KX] = {};
    float sxx0[KX] = {}, sxx1[KX] = {}, sxx2[KX] = {};
    float sxy0[KX] = {}, sxy1[KX] = {}, sxy2[KX] = {};
    float sy0[KX] = {}, sy1[KX] = {}, sy2[KX] = {};
    float sw[KX] = {};

    const float CC = -5.770780163555852f;  // -(4/bw^2) * log2(e)

#define TAPK(k)                                                         \
    {                                                                   \
        float d0 = tp0[k] - t0;                                         \
        float d1 = tp1[k] - t1;                                         \
        float d2 = tp2[k] - t2;                                         \
        float d  = d0 * d0;                                             \
        d = fmaf(d1, d1, d);                                            \
        d = fmaf(d2, d2, d);                                            \
        float w = __builtin_amdgcn_exp2f(d * CC);  /* OOB -> 0 */       \
        float wt0 = w * t0, wt1 = w * t1, wt2 = w * t2;                 \
        sx0[k] += wt0;  sx1[k] += wt1;  sx2[k] += wt2;                  \
        sxx0[k] = fmaf(wt0, t0, sxx0[k]);                               \
        sxx1[k] = fmaf(wt1, t1, sxx1[k]);                               \
        sxx2[k] = fmaf(wt2, t2, sxx2[k]);                               \
        sxy0[k] = fmaf(wt0, r0, sxy0[k]);                               \
        sxy1[k] = fmaf(wt1, r1, sxy1[k]);                               \
        sxy2[k] = fmaf(wt2, r2, sxy2[k]);                               \
        sy0[k]  = fmaf(w, r0, sy0[k]);                                  \
        sy1[k]  = fmaf(w, r1, sy1[k]);                                  \
        sy2[k]  = fmaf(w, r2, sy2[k]);                                  \
        sw[k]  += w;                                                    \
    }

    #pragma unroll 1
    for (int dy = 0; dy < 11; ++dy) {
        const int rb = (ty + dy) * LSTR + tx * KX;   // even -> 8B aligned
        float T0[12], T1[12], T2[12], R0[12], R1[12], R2[12];
        #pragma unroll
        for (int m = 0; m < 6; ++m) {
            *(float2*)&T0[2*m] = *(const float2*)(pt0 + rb + 2*m);
            *(float2*)&T1[2*m] = *(const float2*)(pt1 + rb + 2*m);
            *(float2*)&T2[2*m] = *(const float2*)(pt2 + rb + 2*m);
            *(float2*)&R0[2*m] = *(const float2*)(pr0 + rb + 2*m);
            *(float2*)&R1[2*m] = *(const float2*)(pr1 + rb + 2*m);
            *(float2*)&R2[2*m] = *(const float2*)(pr2 + rb + 2*m);
        }
        #pragma unroll
        for (int j = 0; j < 12; ++j) {
            const float t0 = T0[j], t1 = T1[j], t2 = T2[j];
            const float r0 = R0[j], r1 = R1[j], r2 = R2[j];
            if (j <= 10) TAPK(0)      // k=0: taps j=0..10
            if (j >= 1)  TAPK(1)      // k=1: taps j=1..11
        }
    }
#undef TAPK

    const float inv0 = 1.0f / sw[0];
    const float inv1 = 1.0f / sw[1];

    // ---- epilogue: stage normalized results in LDS (tile order), then
    //      cooperative lane-contiguous float4 stores ----
    __syncthreads();   // everyone done reading the planes

    // chunk c occupies floats [c*1536, (c+1)*1536): 16 rows x 96 floats.
    // thread covers floats [6*tx, 6*tx+6) of its row -> 3 float2 (aligned).
    float2* l2 = (float2*)lds;
    {
        const int b2 = ty * 48 + tx * 3;       // float2 index within chunk
#define STAGE_CHUNK(a0, a1, a2, cidx)                                   \
        {                                                               \
            float2* p = l2 + (cidx) * 768 + b2;                         \
            p[0] = make_float2(a0[0]*inv0, a1[0]*inv0);                 \
            p[1] = make_float2(a2[0]*inv0, a0[1]*inv1);                 \
            p[2] = make_float2(a1[1]*inv1, a2[1]*inv1);                 \
        }
        STAGE_CHUNK(sx0,  sx1,  sx2,  0)
        STAGE_CHUNK(sxx0, sxx1, sxx2, 1)
        STAGE_CHUNK(sxy0, sxy1, sxy2, 2)
        STAGE_CHUNK(sy0,  sy1,  sy2,  3)
#undef STAGE_CHUNK
    }
    __syncthreads();

    const int CH = BB * HH * WW * 3;     // 11,059,200 floats per chunk
    float4* l4 = (float4*)lds;           // 1536 valid float4
    #pragma unroll
    for (int m = 0; m < 6; ++m) {
        const int r = m * 256 + tid;     // 0..1535
        const int c = r / 384;           // chunk
        const int q = r - c * 384;
        const int row = q / 24;          // tile row 0..15
        const int c4  = q - row * 24;    // float4 col within row (24 per row)
        float4 v = l4[r];
        const int gaddr = c * CH + ((b * HH + Y0 + row) * WW + X0) * 3 + c4 * 4;
        *(float4*)(out + gaddr) = v;     // consecutive lanes -> consecutive 16B
    }
}

extern "C" void kernel_launch(void* const* d_in, const int* in_sizes, int n_in,
                              void* d_out, int out_size, void* d_ws, size_t ws_size,
                              hipStream_t stream) {
    const float* rnd = (const float*)d_in[0];   // "rand"
    const float* tgt = (const float*)d_in[1];   // "target"
    float* out = (float*)d_out;

    dim3 grid(WW / TX, HH / TY, BB);   // 40 x 45 x 4 = 7200 blocks, exact tiling
    dim3 block(16, 16);
    regression_kernel<<<grid, block, 0, stream>>>(rnd, tgt, out);
}

// Round 4
// 2349.848 us; speedup vs baseline: 1.0623x; 1.0623x over previous
//
#include <hip/hip_runtime.h>

// Sliding-window bandwidth-weighted regression moments.
// B=4, H=720, W=1280, C=3, win=11 (R=5), bandwidth=0.5 -> inv_bw2=4.
// Outputs (concatenated): x/wsum, xx/wsum, xy/wsum, y/wsum, each [B,H,W,C] fp32.
//
// R6 resubmit (R3 bench was an infra failure, no signal).
// R5 -> R6: fix the spill, keep the occupancy.
//  - R5's whole-row register cache (72 live floats) forced scratch spill
//    (VGPR=40, 12.4 GB HBM scratch traffic). R6 loads per-chunk instead:
//    one float2 per plane (12 floats live), consume 2 columns, next chunk.
//    Max live ~60 VGPR < 85 cap -> no spill.
//  - Everything else from R5 kept: 32x16 tile (KX=2), LSTR=42, 26.2 KB LDS
//    -> 6 blocks/CU (6 waves/SIMD), sentinel OOB masking (no inner-loop
//    bounds logic), __builtin_amdgcn_exp2f, float2/float4 epilogue.

#define HH   720
#define WW   1280
#define BB   4
#define RAD  5
#define TX   32      // tile width  (16 threads x KX=2)
#define TY   16      // tile height (16 threads)
#define KX   2
#define LW   42      // tile cols incl. halo
#define LH   26      // tile rows incl. halo
#define LSTR 42      // == LW; (ty+dy)*42 + tx*2 is even -> 8B-aligned b64 reads
#define PLANE (LSTR * LH)          // 1092 floats
#define LDS_FLOATS (6 * PLANE)     // 6552 floats = 26208 B -> 6 blocks/CU

__global__ __launch_bounds__(256, 6)
void regression_kernel(const float* __restrict__ rnd,
                       const float* __restrict__ tgt,
                       float* __restrict__ out)
{
    __shared__ __align__(16) float lds[LDS_FLOATS];
    float* pt0 = lds;
    float* pt1 = lds + PLANE;
    float* pt2 = lds + 2 * PLANE;
    float* pr0 = lds + 3 * PLANE;
    float* pr1 = lds + 4 * PLANE;
    float* pr2 = lds + 5 * PLANE;

    const int tx = threadIdx.x;        // 0..15
    const int ty = threadIdx.y;        // 0..15
    const int tid = ty * 16 + tx;
    const int X0 = blockIdx.x * TX;
    const int Y0 = blockIdx.y * TY;
    const int b  = blockIdx.z;

    const float SENT = 1e19f;          // OOB sentinel: d ~ 1e38 -> w = 0 exactly

    // ---- stage tile (42x26, sentinel for OOB) into 6 SoA planes ----
    for (int i = tid; i < PLANE; i += 256) {
        int ly = i / LSTR;
        int lx = i - ly * LSTR;
        int gy = Y0 + ly - RAD;
        int gx = X0 + lx - RAD;
        float t0 = SENT, t1 = SENT, t2 = SENT, r0 = 0.f, r1 = 0.f, r2 = 0.f;
        if ((unsigned)gy < (unsigned)HH && (unsigned)gx < (unsigned)WW) {
            int off = ((b * HH + gy) * WW + gx) * 3;
            t0 = tgt[off + 0]; t1 = tgt[off + 1]; t2 = tgt[off + 2];
            r0 = rnd[off + 0]; r1 = rnd[off + 1]; r2 = rnd[off + 2];
        }
        pt0[i] = t0; pt1[i] = t1; pt2[i] = t2;
        pr0[i] = r0; pr1[i] = r1; pr2[i] = r2;
    }
    __syncthreads();

    // ---- center guide colors for the 2-px strip (always in-image) ----
    float tp0[KX], tp1[KX], tp2[KX];
    {
        int s = (ty + RAD) * LSTR + tx * KX + RAD;
        #pragma unroll
        for (int k = 0; k < KX; ++k) {
            tp0[k] = pt0[s + k]; tp1[k] = pt1[s + k]; tp2[k] = pt2[s + k];
        }
    }

    float sx0[KX] = {}, sx1[KX] = {}, sx2[KX] = {};
    float sxx0[KX] = {}, sxx1[KX] = {}, sxx2[KX] = {};
    float sxy0[KX] = {}, sxy1[KX] = {}, sxy2[KX] = {};
    float sy0[KX] = {}, sy1[KX] = {}, sy2[KX] = {};
    float sw[KX] = {};

    const float CC = -5.770780163555852f;  // -(4/bw^2) * log2(e)

    // One tap for strip pixel k against window column values (t0,t1,t2,r0,r1,r2)
#define TAPK(k)                                                         \
    {                                                                   \
        float d0 = tp0[k] - t0;                                         \
        float d1 = tp1[k] - t1;                                         \
        float d2 = tp2[k] - t2;                                         \
        float d  = d0 * d0;                                             \
        d = fmaf(d1, d1, d);                                            \
        d = fmaf(d2, d2, d);                                            \
        float w = __builtin_amdgcn_exp2f(d * CC);  /* OOB -> 0 */       \
        float wt0 = w * t0, wt1 = w * t1, wt2 = w * t2;                 \
        sx0[k] += wt0;  sx1[k] += wt1;  sx2[k] += wt2;                  \
        sxx0[k] = fmaf(wt0, t0, sxx0[k]);                               \
        sxx1[k] = fmaf(wt1, t1, sxx1[k]);                               \
        sxx2[k] = fmaf(wt2, t2, sxx2[k]);                               \
        sxy0[k] = fmaf(wt0, r0, sxy0[k]);                               \
        sxy1[k] = fmaf(wt1, r1, sxy1[k]);                               \
        sxy2[k] = fmaf(wt2, r2, sxy2[k]);                               \
        sy0[k]  = fmaf(w, r0, sy0[k]);                                  \
        sy1[k]  = fmaf(w, r1, sy1[k]);                                  \
        sy2[k]  = fmaf(w, r2, sy2[k]);                                  \
        sw[k]  += w;                                                    \
    }

    // Process one loaded column j (values in scalars) with static guards.
    // k=0 covers taps j=0..10 ; k=1 covers taps j=1..11.
#define COL(jj, t0_, t1_, t2_, r0_, r1_, r2_)                           \
    {                                                                   \
        const float t0 = t0_, t1 = t1_, t2 = t2_;                       \
        const float r0 = r0_, r1 = r1_, r2 = r2_;                       \
        if ((jj) <= 10) TAPK(0)                                         \
        if ((jj) >= 1)  TAPK(1)                                         \
    }

    #pragma unroll 1
    for (int dy = 0; dy < 11; ++dy) {
        const int rb = (ty + dy) * LSTR + tx * KX;   // even -> 8B aligned
        #pragma unroll
        for (int m = 0; m < 6; ++m) {
            // chunk: columns j = 2m, 2m+1 ; 6 x ds_read_b64, 12 floats live
            const float2 t0v = *(const float2*)(pt0 + rb + 2 * m);
            const float2 t1v = *(const float2*)(pt1 + rb + 2 * m);
            const float2 t2v = *(const float2*)(pt2 + rb + 2 * m);
            const float2 r0v = *(const float2*)(pr0 + rb + 2 * m);
            const float2 r1v = *(const float2*)(pr1 + rb + 2 * m);
            const float2 r2v = *(const float2*)(pr2 + rb + 2 * m);
            COL(2 * m,     t0v.x, t1v.x, t2v.x, r0v.x, r1v.x, r2v.x)
            COL(2 * m + 1, t0v.y, t1v.y, t2v.y, r0v.y, r1v.y, r2v.y)
        }
    }
#undef COL
#undef TAPK

    const float inv0 = 1.0f / sw[0];
    const float inv1 = 1.0f / sw[1];

    // ---- epilogue: stage normalized results in LDS (tile order), then
    //      cooperative lane-contiguous float4 stores ----
    __syncthreads();   // everyone done reading the planes

    // chunk c occupies floats [c*1536, (c+1)*1536): 16 rows x 96 floats.
    // thread covers floats [6*tx, 6*tx+6) of its row -> 3 float2 (aligned).
    float2* l2 = (float2*)lds;
    {
        const int b2 = ty * 48 + tx * 3;       // float2 index within chunk
#define STAGE_CHUNK(a0, a1, a2, cidx)                                   \
        {                                                               \
            float2* p = l2 + (cidx) * 768 + b2;                         \
            p[0] = make_float2(a0[0]*inv0, a1[0]*inv0);                 \
            p[1] = make_float2(a2[0]*inv0, a0[1]*inv1);                 \
            p[2] = make_float2(a1[1]*inv1, a2[1]*inv1);                 \
        }
        STAGE_CHUNK(sx0,  sx1,  sx2,  0)
        STAGE_CHUNK(sxx0, sxx1, sxx2, 1)
        STAGE_CHUNK(sxy0, sxy1, sxy2, 2)
        STAGE_CHUNK(sy0,  sy1,  sy2,  3)
#undef STAGE_CHUNK
    }
    __syncthreads();

    const int CH = BB * HH * WW * 3;     // 11,059,200 floats per chunk
    float4* l4 = (float4*)lds;           // 1536 valid float4
    #pragma unroll
    for (int m = 0; m < 6; ++m) {
        const int r = m * 256 + tid;     // 0..1535
        const int c = r / 384;           // chunk
        const int q = r - c * 384;
        const int row = q / 24;          // tile row 0..15
        const int c4  = q - row * 24;    // float4 col within row (24 per row)
        float4 v = l4[r];
        const int gaddr = c * CH + ((b * HH + Y0 + row) * WW + X0) * 3 + c4 * 4;
        *(float4*)(out + gaddr) = v;     // consecutive lanes -> consecutive 16B
    }
}

extern "C" void kernel_launch(void* const* d_in, const int* in_sizes, int n_in,
                              void* d_out, int out_size, void* d_ws, size_t ws_size,
                              hipStream_t stream) {
    const float* rnd = (const float*)d_in[0];   // "rand"
    const float* tgt = (const float*)d_in[1];   // "target"
    float* out = (float*)d_out;

    dim3 grid(WW / TX, HH / TY, BB);   // 40 x 45 x 4 = 7200 blocks, exact tiling
    dim3 block(16, 16);
    regression_kernel<<<grid, block, 0, stream>>>(rnd, tgt, out);
}

// Round 5
// 844.492 us; speedup vs baseline: 2.9560x; 2.7826x over previous
//
#include <hip/hip_runtime.h>

// Sliding-window bandwidth-weighted regression moments.
// B=4, H=720, W=1280, C=3, win=11 (R=5), bandwidth=0.5 -> inv_bw2=4.
// Outputs (concatenated): x/wsum, xx/wsum, xy/wsum, y/wsum, each [B,H,W,C] fp32.
//
// R6 -> R7: ONLY change is __launch_bounds__(256,6) -> (256,4).
//  Empirical hipcc budget law from this session: VGPR cap = 512/(2*arg2)
//  (granule 4): arg2=3 -> 84 (R2-R4 all pinned at 84), arg2=6 -> 40
//  (R5/R6 both pinned at 40 -> forced scratch spill, 11.6 GB HBM traffic).
//  arg2=4 -> cap 64: feasible for this body (live set ~53: 26 accum +
//  6 center + 12 chunk + addressing), and <=64 VGPR is the HW occupancy
//  step for 8 waves/SIMD -> LDS (26.2 KB -> 6 blocks/CU) binds at
//  24 waves/CU (75%).
//  Body unchanged from R6: 32x16 tile (KX=2), LSTR=42, sentinel OOB
//  masking, per-chunk float2 loads (6x ds_read_b64, consume 2 cols),
//  __builtin_amdgcn_exp2f, float2-stage + float4-store epilogue.

#define HH   720
#define WW   1280
#define BB   4
#define RAD  5
#define TX   32      // tile width  (16 threads x KX=2)
#define TY   16      // tile height (16 threads)
#define KX   2
#define LW   42      // tile cols incl. halo
#define LH   26      // tile rows incl. halo
#define LSTR 42      // == LW; (ty+dy)*42 + tx*2 is even -> 8B-aligned b64 reads
#define PLANE (LSTR * LH)          // 1092 floats
#define LDS_FLOATS (6 * PLANE)     // 6552 floats = 26208 B -> 6 blocks/CU

__global__ __launch_bounds__(256, 4)
void regression_kernel(const float* __restrict__ rnd,
                       const float* __restrict__ tgt,
                       float* __restrict__ out)
{
    __shared__ __align__(16) float lds[LDS_FLOATS];
    float* pt0 = lds;
    float* pt1 = lds + PLANE;
    float* pt2 = lds + 2 * PLANE;
    float* pr0 = lds + 3 * PLANE;
    float* pr1 = lds + 4 * PLANE;
    float* pr2 = lds + 5 * PLANE;

    const int tx = threadIdx.x;        // 0..15
    const int ty = threadIdx.y;        // 0..15
    const int tid = ty * 16 + tx;
    const int X0 = blockIdx.x * TX;
    const int Y0 = blockIdx.y * TY;
    const int b  = blockIdx.z;

    const float SENT = 1e19f;          // OOB sentinel: d ~ 1e38 -> w = 0 exactly

    // ---- stage tile (42x26, sentinel for OOB) into 6 SoA planes ----
    for (int i = tid; i < PLANE; i += 256) {
        int ly = i / LSTR;
        int lx = i - ly * LSTR;
        int gy = Y0 + ly - RAD;
        int gx = X0 + lx - RAD;
        float t0 = SENT, t1 = SENT, t2 = SENT, r0 = 0.f, r1 = 0.f, r2 = 0.f;
        if ((unsigned)gy < (unsigned)HH && (unsigned)gx < (unsigned)WW) {
            int off = ((b * HH + gy) * WW + gx) * 3;
            t0 = tgt[off + 0]; t1 = tgt[off + 1]; t2 = tgt[off + 2];
            r0 = rnd[off + 0]; r1 = rnd[off + 1]; r2 = rnd[off + 2];
        }
        pt0[i] = t0; pt1[i] = t1; pt2[i] = t2;
        pr0[i] = r0; pr1[i] = r1; pr2[i] = r2;
    }
    __syncthreads();

    // ---- center guide colors for the 2-px strip (always in-image) ----
    float tp0[KX], tp1[KX], tp2[KX];
    {
        int s = (ty + RAD) * LSTR + tx * KX + RAD;
        #pragma unroll
        for (int k = 0; k < KX; ++k) {
            tp0[k] = pt0[s + k]; tp1[k] = pt1[s + k]; tp2[k] = pt2[s + k];
        }
    }

    float sx0[KX] = {}, sx1[KX] = {}, sx2[KX] = {};
    float sxx0[KX] = {}, sxx1[KX] = {}, sxx2[KX] = {};
    float sxy0[KX] = {}, sxy1[KX] = {}, sxy2[KX] = {};
    float sy0[KX] = {}, sy1[KX] = {}, sy2[KX] = {};
    float sw[KX] = {};

    const float CC = -5.770780163555852f;  // -(4/bw^2) * log2(e)

    // One tap for strip pixel k against window column values (t0,t1,t2,r0,r1,r2)
#define TAPK(k)                                                         \
    {                                                                   \
        float d0 = tp0[k] - t0;                                         \
        float d1 = tp1[k] - t1;                                         \
        float d2 = tp2[k] - t2;                                         \
        float d  = d0 * d0;                                             \
        d = fmaf(d1, d1, d);                                            \
        d = fmaf(d2, d2, d);                                            \
        float w = __builtin_amdgcn_exp2f(d * CC);  /* OOB -> 0 */       \
        float wt0 = w * t0, wt1 = w * t1, wt2 = w * t2;                 \
        sx0[k] += wt0;  sx1[k] += wt1;  sx2[k] += wt2;                  \
        sxx0[k] = fmaf(wt0, t0, sxx0[k]);                               \
        sxx1[k] = fmaf(wt1, t1, sxx1[k]);                               \
        sxx2[k] = fmaf(wt2, t2, sxx2[k]);                               \
        sxy0[k] = fmaf(wt0, r0, sxy0[k]);                               \
        sxy1[k] = fmaf(wt1, r1, sxy1[k]);                               \
        sxy2[k] = fmaf(wt2, r2, sxy2[k]);                               \
        sy0[k]  = fmaf(w, r0, sy0[k]);                                  \
        sy1[k]  = fmaf(w, r1, sy1[k]);                                  \
        sy2[k]  = fmaf(w, r2, sy2[k]);                                  \
        sw[k]  += w;                                                    \
    }

    // Process one loaded column j (values in scalars) with static guards.
    // k=0 covers taps j=0..10 ; k=1 covers taps j=1..11.
#define COL(jj, t0_, t1_, t2_, r0_, r1_, r2_)                           \
    {                                                                   \
        const float t0 = t0_, t1 = t1_, t2 = t2_;                       \
        const float r0 = r0_, r1 = r1_, r2 = r2_;                       \
        if ((jj) <= 10) TAPK(0)                                         \
        if ((jj) >= 1)  TAPK(1)                                         \
    }

    #pragma unroll 1
    for (int dy = 0; dy < 11; ++dy) {
        const int rb = (ty + dy) * LSTR + tx * KX;   // even -> 8B aligned
        #pragma unroll
        for (int m = 0; m < 6; ++m) {
            // chunk: columns j = 2m, 2m+1 ; 6 x ds_read_b64, 12 floats live
            const float2 t0v = *(const float2*)(pt0 + rb + 2 * m);
            const float2 t1v = *(const float2*)(pt1 + rb + 2 * m);
            const float2 t2v = *(const float2*)(pt2 + rb + 2 * m);
            const float2 r0v = *(const float2*)(pr0 + rb + 2 * m);
            const float2 r1v = *(const float2*)(pr1 + rb + 2 * m);
            const float2 r2v = *(const float2*)(pr2 + rb + 2 * m);
            COL(2 * m,     t0v.x, t1v.x, t2v.x, r0v.x, r1v.x, r2v.x)
            COL(2 * m + 1, t0v.y, t1v.y, t2v.y, r0v.y, r1v.y, r2v.y)
        }
    }
#undef COL
#undef TAPK

    const float inv0 = 1.0f / sw[0];
    const float inv1 = 1.0f / sw[1];

    // ---- epilogue: stage normalized results in LDS (tile order), then
    //      cooperative lane-contiguous float4 stores ----
    __syncthreads();   // everyone done reading the planes

    // chunk c occupies floats [c*1536, (c+1)*1536): 16 rows x 96 floats.
    // thread covers floats [6*tx, 6*tx+6) of its row -> 3 float2 (aligned).
    float2* l2 = (float2*)lds;
    {
        const int b2 = ty * 48 + tx * 3;       // float2 index within chunk
#define STAGE_CHUNK(a0, a1, a2, cidx)                                   \
        {                                                               \
            float2* p = l2 + (cidx) * 768 + b2;                         \
            p[0] = make_float2(a0[0]*inv0, a1[0]*inv0);                 \
            p[1] = make_float2(a2[0]*inv0, a0[1]*inv1);                 \
            p[2] = make_float2(a1[1]*inv1, a2[1]*inv1);                 \
        }
        STAGE_CHUNK(sx0,  sx1,  sx2,  0)
        STAGE_CHUNK(sxx0, sxx1, sxx2, 1)
        STAGE_CHUNK(sxy0, sxy1, sxy2, 2)
        STAGE_CHUNK(sy0,  sy1,  sy2,  3)
#undef STAGE_CHUNK
    }
    __syncthreads();

    const int CH = BB * HH * WW * 3;     // 11,059,200 floats per chunk
    float4* l4 = (float4*)lds;           // 1536 valid float4
    #pragma unroll
    for (int m = 0; m < 6; ++m) {
        const int r = m * 256 + tid;     // 0..1535
        const int c = r / 384;           // chunk
        const int q = r - c * 384;
        const int row = q / 24;          // tile row 0..15
        const int c4  = q - row * 24;    // float4 col within row (24 per row)
        float4 v = l4[r];
        const int gaddr = c * CH + ((b * HH + Y0 + row) * WW + X0) * 3 + c4 * 4;
        *(float4*)(out + gaddr) = v;     // consecutive lanes -> consecutive 16B
    }
}

extern "C" void kernel_launch(void* const* d_in, const int* in_sizes, int n_in,
                              void* d_out, int out_size, void* d_ws, size_t ws_size,
                              hipStream_t stream) {
    const float* rnd = (const float*)d_in[0];   // "rand"
    const float* tgt = (const float*)d_in[1];   // "target"
    float* out = (float*)d_out;

    dim3 grid(WW / TX, HH / TY, BB);   // 40 x 45 x 4 = 7200 blocks, exact tiling
    dim3 block(16, 16);
    regression_kernel<<<grid, block, 0, stream>>>(rnd, tgt, out);
}